// Round 9
// baseline (186.902 us; speedup 1.0000x reference)
//
#include <hip/hip_runtime.h>

typedef unsigned short u16;
typedef __bf16 bf16x8 __attribute__((ext_vector_type(8)));
typedef __bf16 bf16x4 __attribute__((ext_vector_type(4)));
typedef float f32x4 __attribute__((ext_vector_type(4)));

__device__ __forceinline__ u16 f2bf(float f) {
    union { float f; unsigned int i; } v; v.f = f;
    unsigned int x = v.i;
    x += 0x7fffu + ((x >> 16) & 1u);   // round-to-nearest-even
    return (u16)(x >> 16);
}

// Async global->LDS 16B copy. LDS dest is wave-uniform base + lane*16.
__device__ __forceinline__ void gl_lds16(const u16* g, u16* l) {
    __builtin_amdgcn_global_load_lds(
        (const __attribute__((address_space(1))) void*)g,
        (__attribute__((address_space(3))) void*)l, 16, 0, 0);
}

// ---------------------------------------------------------------------------
// cvt: fp32 -> bf16, grid-stride. Up to three source ranges in one launch
// (x, w_qkv, and optionally w_out when the workspace has room for it).
// ---------------------------------------------------------------------------
__global__ __launch_bounds__(256, 2)
void cvt_all_kernel(const float* __restrict__ X, const float* __restrict__ Wq,
                    const float* __restrict__ Wo,
                    u16* __restrict__ Xb, u16* __restrict__ Wqb,
                    u16* __restrict__ Wob, int n3)
{
    const int n1 = 4194304 / 4;   // x chunks
    const int n2 = 3145728 / 4;   // w_qkv chunks
    int i = blockIdx.x * 256 + threadIdx.x;
    const int stride = gridDim.x * 256;
    for (; i < n1 + n2 + n3; i += stride) {
        float4 v;
        ushort4* dst;
        if (i < n1)           { v = ((const float4*)X)[i];            dst = (ushort4*)Xb  + i; }
        else if (i < n1 + n2) { v = ((const float4*)Wq)[i - n1];      dst = (ushort4*)Wqb + (i - n1); }
        else                  { v = ((const float4*)Wo)[i - n1 - n2]; dst = (ushort4*)Wob + (i - n1 - n2); }
        ushort4 o;
        o.x = f2bf(v.x); o.y = f2bf(v.y); o.z = f2bf(v.z); o.w = f2bf(v.w);
        *dst = o;
    }
}

__global__ __launch_bounds__(256, 2)
void cvt_w_kernel(const float* __restrict__ W, u16* __restrict__ Wb)
{
    int i = blockIdx.x * 256 + threadIdx.x;     // 262144 chunks, grid covers exactly
    float4 v = ((const float4*)W)[i];
    ushort4 o;
    o.x = f2bf(v.x); o.y = f2bf(v.y); o.z = f2bf(v.z); o.w = f2bf(v.w);
    ((ushort4*)Wb)[i] = o;
}

// ---------------------------------------------------------------------------
// Kernel 1: qkv = x @ w_qkv^T (M=4096,N=3072,K=1024), bf16 in, RoPE epilogue.
// m97 pattern: global_load_lds 16B staging into unpadded XOR-swizzled LDS.
// V-blocks (n0>=2048) use packed 8B epilogue stores (4 consecutive t / lane).
// ---------------------------------------------------------------------------
__global__ __launch_bounds__(256, 3)
void qkv_rope_kernel(const u16* __restrict__ X, const u16* __restrict__ W,
                     const float* __restrict__ Cos, const float* __restrict__ Sin,
                     u16* __restrict__ Qo, u16* __restrict__ Ko, u16* __restrict__ Vo)
{
    __shared__ __align__(16) u16 As[128 * 64];
    __shared__ __align__(16) u16 Bs[128 * 64];
    const int tid  = threadIdx.x;
    const int lane = tid & 63, wave = tid >> 6;
    const int l15  = lane & 15, q4 = lane >> 4;
    const int wm = (wave >> 1) * 64, wn = (wave & 1) * 64;
    const int m0 = blockIdx.y * 128, n0 = blockIdx.x * 128;
    const int srow = lane >> 3;
    const int scol = ((lane & 7) ^ srow) * 8;

    f32x4 acc[4][4];
    #pragma unroll
    for (int i = 0; i < 4; i++)
        #pragma unroll
        for (int j = 0; j < 4; j++) { f32x4 z = {}; acc[i][j] = z; }

    for (int k0 = 0; k0 < 1024; k0 += 64) {
        __syncthreads();
        #pragma unroll
        for (int i = 0; i < 4; i++) {
            int rb = wave * 32 + i * 8;
            gl_lds16(X + (size_t)(m0 + rb + srow) * 1024 + k0 + scol, As + rb * 64);
            gl_lds16(W + (size_t)(n0 + rb + srow) * 1024 + k0 + scol, Bs + rb * 64);
        }
        __syncthreads();
        #pragma unroll
        for (int ks = 0; ks < 2; ks++) {
            const int ch = (((4 * ks + q4) ^ (l15 & 7)) * 8);
            bf16x8 af[4], bfr[4];
            #pragma unroll
            for (int i = 0; i < 4; i++) {
                af[i]  = *(const bf16x8*)&As[(wm + i * 16 + l15) * 64 + ch];
                bfr[i] = *(const bf16x8*)&Bs[(wn + i * 16 + l15) * 64 + ch];
            }
            #pragma unroll
            for (int mi = 0; mi < 4; mi++)
                #pragma unroll
                for (int ni = 0; ni < 4; ni++)
                    acc[mi][ni] = __builtin_amdgcn_mfma_f32_16x16x32_bf16(
                        af[mi], bfr[ni], acc[mi][ni], 0, 0, 0);
        }
    }

    if (n0 >= 2048) {
        // Pure-V block: packed stores, 4 t-consecutive values per 8B.
        #pragma unroll
        for (int mi = 0; mi < 4; mi++) {
            int t0row = m0 + wm + mi * 16 + q4 * 4;       // global m, 4-aligned
            int b = t0row >> 11, t0 = t0row & 2047;
            #pragma unroll
            for (int ni = 0; ni < 4; ni++) {
                int col = n0 + wn + ni * 16 + l15;
                int hh  = (col >> 6) & 15;
                int d   = col & 63;
                ushort4 pk;
                pk.x = f2bf(acc[mi][ni][0]); pk.y = f2bf(acc[mi][ni][1]);
                pk.z = f2bf(acc[mi][ni][2]); pk.w = f2bf(acc[mi][ni][3]);
                *(ushort4*)&Vo[(((size_t)(b * 16 + hh)) * 64 + d) * 2048 + t0] = pk;
            }
        }
    } else {
        // Q/K block: RoPE epilogue. C/D layout col=lane&15, row=quad*4+reg.
        #pragma unroll
        for (int mi = 0; mi < 4; mi++) {
            #pragma unroll
            for (int r = 0; r < 4; r++) {
                int row = m0 + wm + mi * 16 + q4 * 4 + r;
                int b = row >> 11, t = row & 2047;
                #pragma unroll
                for (int ni = 0; ni < 4; ni++) {
                    int col = n0 + wn + ni * 16 + l15;
                    float v = acc[mi][ni][r];
                    int sec = col >> 10;
                    int hh  = (col >> 6) & 15;
                    int d   = col & 63;
                    float cs = Cos[t * 64 + d];
                    float sn = Sin[t * 64 + d];
                    float partner = acc[mi][ni ^ 2][r];   // col ^ 32, same lane
                    float rot = (d < 32) ? -partner : partner;
                    v = v * cs + rot * sn;
                    u16* dst = (sec == 0) ? Qo : Ko;
                    dst[(((size_t)(b * 16 + hh)) * 2048 + t) * 64 + d] = f2bf(v);
                }
            }
        }
    }
}

// ---------------------------------------------------------------------------
// Kernel 2: causal flash attention, S^T formulation, KV-tile = 128.
// R8 inner loop unchanged (2-barrier, K(it+1) prefetched direct into Ks —
// clean traffic, VGPR 84). NEW: 8-WAVE blocks over 128 q-rows. Rationale:
// R2/R5/R8 all ~44us at 3 waves/SIMD; R6 dose-response (3->2 waves/SIMD =
// -10%) says the kernel is per-wave-latency-bound -> raise waves/SIMD.
// 8 waves share Ks/Vs (staging 2 issues/wave); Ps[8][16][136]; LDS 67584
// -> 2 blocks/CU by LDS = 16 waves/CU = 4 waves/SIMD. (512,2) keeps the
// VGPR cap at 256 so regalloc is NOT squeezed (R3 lesson) — LDS caps
// occupancy instead. Grid 512 = 2/CU static; complementary tile map
// (slot<8 ? 15-slot : slot-8) pairs big+small blocks per CU (sum nkv=17
// uniform) to dodge the R6 static-imbalance trap. Defer-max THR=8 kept.
// ---------------------------------------------------------------------------
__global__ __launch_bounds__(512, 2)
void attn_kernel(const u16* __restrict__ Q, const u16* __restrict__ Kg,
                 const u16* __restrict__ Vt, u16* __restrict__ Oh)
{
    __shared__ __align__(16) u16 Ks[128 * 64];    // [kv][d]   8-chunk rows, ^(row&7)
    __shared__ __align__(16) u16 Vs[64 * 128];    // [d][kv]  16-chunk rows, ^(d&15)
    __shared__ __align__(16) __bf16 Ps[8][16][136];

    const int bx = blockIdx.x;
    const int xcd = bx & 7;
    const int i8  = bx >> 3;            // 0..63 per XCD
    const int bh  = xcd * 4 + (i8 & 3); // 4 heads per XCD
    const int slot = i8 >> 2;           // 0..15
    const int j  = (slot < 8) ? (15 - slot) : (slot - 8);  // 128-row q-tile
    const int b = bh >> 4, h = bh & 15;
    const int tid = threadIdx.x, wave = tid >> 6, lane = tid & 63;
    const int l15 = lane & 15, q4 = lane >> 4;
    const int srow = lane >> 3;
    const int sKcol = ((lane & 7) ^ srow) * 8;

    const size_t head_off = (size_t)bh * 2048 * 64;
    const u16* Qb = Q  + head_off;
    const u16* Kb = Kg + head_off;
    const u16* Vb = Vt + head_off;     // [d][t] per head

    const int qrow0 = j * 128 + wave * 16;   // this wave's 16 q-rows

    // Q fragments (B operand): B[n=l15][k=q4*8+jj+32*ks], pre-scaled by
    // 0.125*log2(e): softmax moves to exp2 domain.
    const float QSCALE = 0.18033688f;
    bf16x8 qf[2];
    #pragma unroll
    for (int ks = 0; ks < 2; ks++) {
        bf16x8 t = *(const bf16x8*)(Qb + (size_t)(qrow0 + l15) * 64 + ks * 32 + q4 * 8);
        #pragma unroll
        for (int jj = 0; jj < 8; jj++) t[jj] = (__bf16)((float)t[jj] * QSCALE);
        qf[ks] = t;
    }

    bf16x8 ones;
    #pragma unroll
    for (int jj = 0; jj < 8; jj++) ones[jj] = (__bf16)1.0f;

    f32x4 o[4];                       // O rows q=qrow0+q4*4+r, cols d=ni*16+l15
    f32x4 ol = {};                    // row-sum accumulator
    float mstq = -1e30f;              // running max (log2 domain), lane's q=l15
    #pragma unroll
    for (int ni = 0; ni < 4; ni++) { f32x4 z = {}; o[ni] = z; }

    const int nkv = j + 1;             // 128-wide kv tiles (block-uniform)

    // Prologue: stage K(0), one barrier (vmcnt(0) drains it). 2 issues/wave.
    #pragma unroll
    for (int i = 0; i < 2; i++) {
        int rb = (wave * 2 + i) * 8;
        gl_lds16(Kb + (size_t)(rb + srow) * 64 + sKcol, Ks + rb * 64);
    }
    __syncthreads();                   // K(0) in LDS, visible block-wide

    for (int it = 0; it < nkv; it++) {
        const int k0 = it * 128;
        // Issue V(it): in flight through the whole S phase. 2 issues/wave.
        #pragma unroll
        for (int i = 0; i < 2; i++) {
            int rb = (wave * 2 + i) * 4;
            int d  = rb + (lane >> 4);
            int cl = ((lane & 15) ^ (d & 15)) * 8;
            gl_lds16(Vb + (size_t)d * 2048 + k0 + cl, Vs + rb * 128);
        }

        // S^T = K Q^T : st[half][mi][r]: kv = half*64+mi*16+q4*4+r, q = l15
        f32x4 st[2][4];
        #pragma unroll
        for (int hf = 0; hf < 2; hf++)
            #pragma unroll
            for (int mi = 0; mi < 4; mi++) { f32x4 z = {}; st[hf][mi] = z; }
        #pragma unroll
        for (int ks = 0; ks < 2; ks++) {
            const int ch = (((4 * ks + q4) ^ (l15 & 7)) * 8);
            #pragma unroll
            for (int hf = 0; hf < 2; hf++) {
                bf16x8 kf[4];
                #pragma unroll
                for (int mi = 0; mi < 4; mi++)
                    kf[mi] = *(const bf16x8*)&Ks[(hf * 64 + mi * 16 + l15) * 64 + ch];
                #pragma unroll
                for (int mi = 0; mi < 4; mi++)
                    st[hf][mi] = __builtin_amdgcn_mfma_f32_16x16x32_bf16(
                        kf[mi], qf[ks], st[hf][mi], 0, 0, 0);
            }
        }

        // mask (last tile only) + row max: in-reg tree + 2 shuffle stages
        float rm = -1e30f;
        if (it == nkv - 1) {
            const int tq = qrow0 + l15;
            #pragma unroll
            for (int hf = 0; hf < 2; hf++)
                #pragma unroll
                for (int mi = 0; mi < 4; mi++)
                    #pragma unroll
                    for (int r = 0; r < 4; r++) {
                        float v = st[hf][mi][r];
                        if (k0 + hf * 64 + mi * 16 + q4 * 4 + r > tq) v = -1e30f;
                        st[hf][mi][r] = v;
                        rm = fmaxf(rm, v);
                    }
        } else {
            #pragma unroll
            for (int hf = 0; hf < 2; hf++)
                #pragma unroll
                for (int mi = 0; mi < 4; mi++)
                    #pragma unroll
                    for (int r = 0; r < 4; r++)
                        rm = fmaxf(rm, st[hf][mi][r]);
        }
        rm = fmaxf(rm, __shfl_xor(rm, 16, 64));
        rm = fmaxf(rm, __shfl_xor(rm, 32, 64));

        // Defer-max (T13): only update m (and rescale) when max grew past 8.
        const float mold = mstq;
        const bool need = __any(rm > mstq + 8.0f);
        if (need) mstq = fmaxf(mstq, rm);

        // exp2 + write P^T rows (q = l15) to Ps: 8B stores BEFORE B1 —
        // overlaps V-load latency, no cross-barrier register life.
        #pragma unroll
        for (int hf = 0; hf < 2; hf++)
            #pragma unroll
            for (int mi = 0; mi < 4; mi++) {
                bf16x4 p4;
                #pragma unroll
                for (int r = 0; r < 4; r++)
                    p4[r] = (__bf16)exp2f(st[hf][mi][r] - mstq);
                *(bf16x4*)&Ps[wave][l15][hf * 64 + mi * 16 + q4 * 4] = p4;
            }

        // alpha to row orientation: flat shuffles (only when max moved)
        if (need) {
            float alpha = exp2f(mold - mstq);
            float ar[4];
            #pragma unroll
            for (int r = 0; r < 4; r++)
                ar[r] = __shfl(alpha, q4 * 4 + r, 64);
            #pragma unroll
            for (int ni = 0; ni < 4; ni++)
                #pragma unroll
                for (int r = 0; r < 4; r++)
                    o[ni][r] *= ar[r];
            #pragma unroll
            for (int r = 0; r < 4; r++)
                ol[r] *= ar[r];
        }

        __syncthreads();   // B1: V(it) ready; all waves' Ks(it) reads done

        // Prefetch K(it+1) DIRECTLY into Ks (async LDS-writes land during
        // PV; PV never reads Ks). Block-uniform guard. Drained+published
        // by B2's vmcnt(0)+barrier.
        if (it + 1 < nkv) {
            const int k0n = k0 + 128;
            #pragma unroll
            for (int i = 0; i < 2; i++) {
                int rb = (wave * 2 + i) * 8;
                gl_lds16(Kb + (size_t)(k0n + rb + srow) * 64 + sKcol, Ks + rb * 64);
            }
        }

        // O += P V ; l += P·1  (contraction over kv=128, 4 ks-steps)
        #pragma unroll
        for (int ks = 0; ks < 4; ks++) {
            bf16x8 pa = *(const bf16x8*)&Ps[wave][l15][ks * 32 + q4 * 8];
            bf16x8 vf[4];
            #pragma unroll
            for (int ni = 0; ni < 4; ni++) {
                const int pc = (((ks * 4 + q4) ^ l15) * 8);   // d&15 == l15
                vf[ni] = *(const bf16x8*)&Vs[(ni * 16 + l15) * 128 + pc];
            }
            #pragma unroll
            for (int ni = 0; ni < 4; ni++)
                o[ni] = __builtin_amdgcn_mfma_f32_16x16x32_bf16(pa, vf[ni], o[ni], 0, 0, 0);
            ol = __builtin_amdgcn_mfma_f32_16x16x32_bf16(pa, ones, ol, 0, 0, 0);
        }

        __syncthreads();   // B2: Ks(it+1) drained+visible; Vs/Ps readers done
    }

    // Epilogue: O / l -> Oh[b,t,h,d] (= [4096,1024] rows)
    #pragma unroll
    for (int r = 0; r < 4; r++) {
        int t = qrow0 + q4 * 4 + r;
        float inv = 1.0f / ol[r];
        #pragma unroll
        for (int ni = 0; ni < 4; ni++) {
            int d = ni * 16 + l15;
            Oh[(((size_t)(b * 2048 + t)) * 16 + h) * 64 + d] = f2bf(o[ni][r] * inv);
        }
    }
}

// ---------------------------------------------------------------------------
// Kernel 3: out = Oh @ w_out^T (M=4096,N=1024,K=1024), fp32 out.
// BM=128, BN=64, BK=64: per-wave 64x32 acc[4][2] -> MFMA:ds_read = 16:12.
// Grid 16x32 = 512 blocks; LDS 24KB, (256,3).
// ---------------------------------------------------------------------------
__global__ __launch_bounds__(256, 3)
void outproj_kernel(const u16* __restrict__ A, const u16* __restrict__ W,
                    float* __restrict__ Cout)
{
    __shared__ __align__(16) u16 As[128 * 64];
    __shared__ __align__(16) u16 Bs[64 * 64];
    const int tid  = threadIdx.x;
    const int lane = tid & 63, wave = tid >> 6;
    const int l15  = lane & 15, q4 = lane >> 4;
    const int wm = (wave >> 1) * 64, wn = (wave & 1) * 32;
    const int m0 = blockIdx.y * 128, n0 = blockIdx.x * 64;
    const int srow = lane >> 3;
    const int scol = ((lane & 7) ^ srow) * 8;

    f32x4 acc[4][2];
    #pragma unroll
    for (int i = 0; i < 4; i++)
        #pragma unroll
        for (int j = 0; j < 2; j++) { f32x4 z = {}; acc[i][j] = z; }

    for (int k0 = 0; k0 < 1024; k0 += 64) {
        __syncthreads();
        #pragma unroll
        for (int i = 0; i < 6; i++) {           // 24 issues: 16 A + 8 B, 8-row each
            int id = wave * 6 + i;              // wave-uniform
            if (id < 16) {
                int rb = id * 8;
                gl_lds16(A + (size_t)(m0 + rb + srow) * 1024 + k0 + scol, As + rb * 64);
            } else {
                int rb = (id - 16) * 8;
                gl_lds16(W + (size_t)(n0 + rb + srow) * 1024 + k0 + scol, Bs + rb * 64);
            }
        }
        __syncthreads();
        #pragma unroll
        for (int ks = 0; ks < 2; ks++) {
            const int ch = (((ks * 4 + q4) ^ (l15 & 7)) * 8);
            bf16x8 af[4], bfr[2];
            #pragma unroll
            for (int i = 0; i < 4; i++)
                af[i]  = *(const bf16x8*)&As[(wm + i * 16 + l15) * 64 + ch];
            #pragma unroll
            for (int j = 0; j < 2; j++)
                bfr[j] = *(const bf16x8*)&Bs[(wn + j * 16 + l15) * 64 + ch];
            #pragma unroll
            for (int mi = 0; mi < 4; mi++)
                #pragma unroll
                for (int ni = 0; ni < 2; ni++)
                    acc[mi][ni] = __builtin_amdgcn_mfma_f32_16x16x32_bf16(
                        af[mi], bfr[ni], acc[mi][ni], 0, 0, 0);
        }
    }

    #pragma unroll
    for (int mi = 0; mi < 4; mi++)
        #pragma unroll
        for (int r = 0; r < 4; r++) {
            int row = m0 + wm + mi * 16 + q4 * 4 + r;
            #pragma unroll
            for (int ni = 0; ni < 2; ni++) {
                int col = n0 + wn + ni * 16 + l15;
                Cout[(size_t)row * 1024 + col] = acc[mi][ni][r];
            }
        }
}

extern "C" void kernel_launch(void* const* d_in, const int* in_sizes, int n_in,
                              void* d_out, int out_size, void* d_ws, size_t ws_size,
                              hipStream_t stream) {
    (void)in_sizes; (void)n_in; (void)out_size;
    const float* x     = (const float*)d_in[0];   // [2,2048,1024] fp32
    const float* cosp  = (const float*)d_in[1];   // [2048,64] fp32
    const float* sinp  = (const float*)d_in[2];   // [2048,64] fp32
    const float* w_qkv = (const float*)d_in[3];   // [3072,1024] fp32
    const float* w_out = (const float*)d_in[4];   // [1024,1024] fp32
    float* out = (float*)d_out;                   // [2,2048,1024] fp32

    const size_t NELEM = (size_t)2 * 2048 * 1024;  // 4,194,304
    // d_out (16.8 MB fp32): Q bf16 in lower half, X bf16 in upper half.
    // Both dead before outproj overwrites all of d_out.
    u16* Q   = (u16*)d_out;            // [b,h,t,d]
    u16* Xb  = (u16*)d_out + NELEM;    // [4096,1024] bf16
    // ws: K 8MB | Vt 8MB | Oh 8MB (+ Wqb aliasing Oh) [+ Wob @24MB if room]
    u16* K   = (u16*)d_ws;             // [b,h,t,d]
    u16* Vt  = K + NELEM;              // [b,h,d,t]
    u16* Oh  = Vt + NELEM;             // [b,t,h,d]
    u16* Wqb = Oh;                     // w_qkv bf16 — dead before attn writes Oh

    const bool big = ws_size >= (24u * 1024 * 1024 + 2u * 1024 * 1024);
    if (big) {
        u16* Wob = K + 3 * NELEM;      // own slot at ws+24MB (2MB)
        cvt_all_kernel<<<7168, 256, 0, stream>>>(x, w_qkv, w_out, Xb, Wqb, Wob,
                                                 262144);
        qkv_rope_kernel<<<dim3(24, 32), 256, 0, stream>>>(Xb, Wqb, cosp, sinp, Q, K, Vt);
        attn_kernel<<<512, 512, 0, stream>>>(Q, K, Vt, Oh);
        outproj_kernel<<<dim3(16, 32), 256, 0, stream>>>(Oh, Wob, out);
    } else {
        u16* Wob = K;                  // w_out bf16 — written after attn (K dead)
        cvt_all_kernel<<<7168, 256, 0, stream>>>(x, w_qkv, w_out, Xb, Wqb, Wob, 0);
        qkv_rope_kernel<<<dim3(24, 32), 256, 0, stream>>>(Xb, Wqb, cosp, sinp, Q, K, Vt);
        attn_kernel<<<512, 512, 0, stream>>>(Q, K, Vt, Oh);
        cvt_w_kernel<<<1024, 256, 0, stream>>>(w_out, Wob);
        outproj_kernel<<<dim3(16, 32), 256, 0, stream>>>(Oh, Wob, out);
    }
}

// Round 10
// 173.392 us; speedup vs baseline: 1.0779x; 1.0779x over previous
//
#include <hip/hip_runtime.h>

typedef unsigned short u16;
typedef __bf16 bf16x8 __attribute__((ext_vector_type(8)));
typedef __bf16 bf16x4 __attribute__((ext_vector_type(4)));
typedef float f32x4 __attribute__((ext_vector_type(4)));

__device__ __forceinline__ u16 f2bf(float f) {
    union { float f; unsigned int i; } v; v.f = f;
    unsigned int x = v.i;
    x += 0x7fffu + ((x >> 16) & 1u);   // round-to-nearest-even
    return (u16)(x >> 16);
}

// Async global->LDS 16B copy. LDS dest is wave-uniform base + lane*16.
__device__ __forceinline__ void gl_lds16(const u16* g, u16* l) {
    __builtin_amdgcn_global_load_lds(
        (const __attribute__((address_space(1))) void*)g,
        (__attribute__((address_space(3))) void*)l, 16, 0, 0);
}

// ---------------------------------------------------------------------------
// cvt: fp32 -> bf16, grid-stride. Up to three source ranges in one launch
// (x, w_qkv, and optionally w_out when the workspace has room for it).
// ---------------------------------------------------------------------------
__global__ __launch_bounds__(256, 2)
void cvt_all_kernel(const float* __restrict__ X, const float* __restrict__ Wq,
                    const float* __restrict__ Wo,
                    u16* __restrict__ Xb, u16* __restrict__ Wqb,
                    u16* __restrict__ Wob, int n3)
{
    const int n1 = 4194304 / 4;   // x chunks
    const int n2 = 3145728 / 4;   // w_qkv chunks
    int i = blockIdx.x * 256 + threadIdx.x;
    const int stride = gridDim.x * 256;
    for (; i < n1 + n2 + n3; i += stride) {
        float4 v;
        ushort4* dst;
        if (i < n1)           { v = ((const float4*)X)[i];            dst = (ushort4*)Xb  + i; }
        else if (i < n1 + n2) { v = ((const float4*)Wq)[i - n1];      dst = (ushort4*)Wqb + (i - n1); }
        else                  { v = ((const float4*)Wo)[i - n1 - n2]; dst = (ushort4*)Wob + (i - n1 - n2); }
        ushort4 o;
        o.x = f2bf(v.x); o.y = f2bf(v.y); o.z = f2bf(v.z); o.w = f2bf(v.w);
        *dst = o;
    }
}

__global__ __launch_bounds__(256, 2)
void cvt_w_kernel(const float* __restrict__ W, u16* __restrict__ Wb)
{
    int i = blockIdx.x * 256 + threadIdx.x;     // 262144 chunks, grid covers exactly
    float4 v = ((const float4*)W)[i];
    ushort4 o;
    o.x = f2bf(v.x); o.y = f2bf(v.y); o.z = f2bf(v.z); o.w = f2bf(v.w);
    ((ushort4*)Wb)[i] = o;
}

// ---------------------------------------------------------------------------
// Kernel 1: qkv = x @ w_qkv^T (M=4096,N=3072,K=1024), bf16 in, RoPE epilogue.
// m97 pattern: global_load_lds 16B staging into unpadded XOR-swizzled LDS.
// V-blocks (n0>=2048) use packed 8B epilogue stores (4 consecutive t / lane).
// ---------------------------------------------------------------------------
__global__ __launch_bounds__(256, 3)
void qkv_rope_kernel(const u16* __restrict__ X, const u16* __restrict__ W,
                     const float* __restrict__ Cos, const float* __restrict__ Sin,
                     u16* __restrict__ Qo, u16* __restrict__ Ko, u16* __restrict__ Vo)
{
    __shared__ __align__(16) u16 As[128 * 64];
    __shared__ __align__(16) u16 Bs[128 * 64];
    const int tid  = threadIdx.x;
    const int lane = tid & 63, wave = tid >> 6;
    const int l15  = lane & 15, q4 = lane >> 4;
    const int wm = (wave >> 1) * 64, wn = (wave & 1) * 64;
    const int m0 = blockIdx.y * 128, n0 = blockIdx.x * 128;
    const int srow = lane >> 3;
    const int scol = ((lane & 7) ^ srow) * 8;

    f32x4 acc[4][4];
    #pragma unroll
    for (int i = 0; i < 4; i++)
        #pragma unroll
        for (int j = 0; j < 4; j++) { f32x4 z = {}; acc[i][j] = z; }

    for (int k0 = 0; k0 < 1024; k0 += 64) {
        __syncthreads();
        #pragma unroll
        for (int i = 0; i < 4; i++) {
            int rb = wave * 32 + i * 8;
            gl_lds16(X + (size_t)(m0 + rb + srow) * 1024 + k0 + scol, As + rb * 64);
            gl_lds16(W + (size_t)(n0 + rb + srow) * 1024 + k0 + scol, Bs + rb * 64);
        }
        __syncthreads();
        #pragma unroll
        for (int ks = 0; ks < 2; ks++) {
            const int ch = (((4 * ks + q4) ^ (l15 & 7)) * 8);
            bf16x8 af[4], bfr[4];
            #pragma unroll
            for (int i = 0; i < 4; i++) {
                af[i]  = *(const bf16x8*)&As[(wm + i * 16 + l15) * 64 + ch];
                bfr[i] = *(const bf16x8*)&Bs[(wn + i * 16 + l15) * 64 + ch];
            }
            #pragma unroll
            for (int mi = 0; mi < 4; mi++)
                #pragma unroll
                for (int ni = 0; ni < 4; ni++)
                    acc[mi][ni] = __builtin_amdgcn_mfma_f32_16x16x32_bf16(
                        af[mi], bfr[ni], acc[mi][ni], 0, 0, 0);
        }
    }

    if (n0 >= 2048) {
        // Pure-V block: packed stores, 4 t-consecutive values per 8B.
        #pragma unroll
        for (int mi = 0; mi < 4; mi++) {
            int t0row = m0 + wm + mi * 16 + q4 * 4;       // global m, 4-aligned
            int b = t0row >> 11, t0 = t0row & 2047;
            #pragma unroll
            for (int ni = 0; ni < 4; ni++) {
                int col = n0 + wn + ni * 16 + l15;
                int hh  = (col >> 6) & 15;
                int d   = col & 63;
                ushort4 pk;
                pk.x = f2bf(acc[mi][ni][0]); pk.y = f2bf(acc[mi][ni][1]);
                pk.z = f2bf(acc[mi][ni][2]); pk.w = f2bf(acc[mi][ni][3]);
                *(ushort4*)&Vo[(((size_t)(b * 16 + hh)) * 64 + d) * 2048 + t0] = pk;
            }
        }
    } else {
        // Q/K block: RoPE epilogue. C/D layout col=lane&15, row=quad*4+reg.
        #pragma unroll
        for (int mi = 0; mi < 4; mi++) {
            #pragma unroll
            for (int r = 0; r < 4; r++) {
                int row = m0 + wm + mi * 16 + q4 * 4 + r;
                int b = row >> 11, t = row & 2047;
                #pragma unroll
                for (int ni = 0; ni < 4; ni++) {
                    int col = n0 + wn + ni * 16 + l15;
                    float v = acc[mi][ni][r];
                    int sec = col >> 10;
                    int hh  = (col >> 6) & 15;
                    int d   = col & 63;
                    float cs = Cos[t * 64 + d];
                    float sn = Sin[t * 64 + d];
                    float partner = acc[mi][ni ^ 2][r];   // col ^ 32, same lane
                    float rot = (d < 32) ? -partner : partner;
                    v = v * cs + rot * sn;
                    u16* dst = (sec == 0) ? Qo : Ko;
                    dst[(((size_t)(b * 16 + hh)) * 2048 + t) * 64 + d] = f2bf(v);
                }
            }
        }
    }
}

// ---------------------------------------------------------------------------
// Kernel 2: causal flash attention, S^T formulation, KV-tile = 128.
// EXACT R8 structure (best measured: attn 44.4us, total 171.3us; VGPR 84,
// FETCH 12.4MB, WRITE 8.2MB, 2-barrier loop, K(it+1) gl_lds16-prefetched
// into Ks during PV). R9 post-mortem: 8-wave blocks regressed (54.5us,
// occupancy 15.6%) — occupancy axis closed both directions; 4-wave x
// 3 blocks/CU is the local optimum of this structure.
// ONLY change vs R8: T5 s_setprio(1) around the two MFMA clusters.
// Mechanism: 3 independent blocks/CU are at different phases; boosting
// MFMA-entering waves keeps the matrix pipe fed (guide m191: +4-7% attn).
// ---------------------------------------------------------------------------
__global__ __launch_bounds__(256, 3)
void attn_kernel(const u16* __restrict__ Q, const u16* __restrict__ Kg,
                 const u16* __restrict__ Vt, u16* __restrict__ Oh)
{
    __shared__ __align__(16) u16 Ks[128 * 64];    // [kv][d]   8-chunk rows, ^(row&7)
    __shared__ __align__(16) u16 Vs[64 * 128];    // [d][kv]  16-chunk rows, ^(d&15)
    __shared__ __align__(16) __bf16 Ps[4][16][136];

    const int bx = blockIdx.x;
    const int xcd = bx & 7;
    const int i8  = bx >> 3;            // 0..127 per XCD
    const int bh  = xcd * 4 + (i8 & 3); // 4 heads per XCD
    const int qt  = 31 - (i8 >> 2);     // longest q-tiles first (LPT)
    const int b = bh >> 4, h = bh & 15;
    const int tid = threadIdx.x, wave = tid >> 6, lane = tid & 63;
    const int l15 = lane & 15, q4 = lane >> 4;
    const int srow = lane >> 3;
    const int sKcol = ((lane & 7) ^ srow) * 8;

    const size_t head_off = (size_t)bh * 2048 * 64;
    const u16* Qb = Q  + head_off;
    const u16* Kb = Kg + head_off;
    const u16* Vb = Vt + head_off;     // [d][t] per head

    const int qrow0 = qt * 64 + wave * 16;   // this wave's 16 q-rows

    // Q fragments (B operand): B[n=l15][k=q4*8+j+32*ks], pre-scaled by
    // 0.125*log2(e): softmax moves to exp2 domain.
    const float QSCALE = 0.18033688f;
    bf16x8 qf[2];
    #pragma unroll
    for (int ks = 0; ks < 2; ks++) {
        bf16x8 t = *(const bf16x8*)(Qb + (size_t)(qrow0 + l15) * 64 + ks * 32 + q4 * 8);
        #pragma unroll
        for (int j = 0; j < 8; j++) t[j] = (__bf16)((float)t[j] * QSCALE);
        qf[ks] = t;
    }

    bf16x8 ones;
    #pragma unroll
    for (int j = 0; j < 8; j++) ones[j] = (__bf16)1.0f;

    f32x4 o[4];                       // O rows q=qrow0+q4*4+r, cols d=ni*16+l15
    f32x4 ol = {};                    // row-sum accumulator
    float mstq = -1e30f;              // running max (log2 domain), lane's q=l15
    #pragma unroll
    for (int ni = 0; ni < 4; ni++) { f32x4 z = {}; o[ni] = z; }

    const int nkv = (qt >> 1) + 1;     // 128-wide kv tiles (block-uniform)

    // Prologue: stage K(0), one barrier (vmcnt(0) drains it).
    #pragma unroll
    for (int i = 0; i < 4; i++) {
        int rb = (wave * 4 + i) * 8;
        gl_lds16(Kb + (size_t)(rb + srow) * 64 + sKcol, Ks + rb * 64);
    }
    __syncthreads();                   // K(0) in LDS, visible block-wide

    for (int it = 0; it < nkv; it++) {
        const int k0 = it * 128;
        // Issue V(it): in flight through the whole S phase.
        // (Vs free: prior PV readers drained at B2 / prologue barrier.)
        #pragma unroll
        for (int i = 0; i < 4; i++) {
            int rb = (wave * 4 + i) * 4;
            int d  = rb + (lane >> 4);
            int cl = ((lane & 15) ^ (d & 15)) * 8;
            gl_lds16(Vb + (size_t)d * 2048 + k0 + cl, Vs + rb * 128);
        }

        // S^T = K Q^T : st[half][mi][r]: kv = half*64+mi*16+q4*4+r, q = l15
        f32x4 st[2][4];
        #pragma unroll
        for (int hf = 0; hf < 2; hf++)
            #pragma unroll
            for (int mi = 0; mi < 4; mi++) { f32x4 z = {}; st[hf][mi] = z; }
        __builtin_amdgcn_s_setprio(1);             // T5: favor MFMA cluster
        #pragma unroll
        for (int ks = 0; ks < 2; ks++) {
            const int ch = (((4 * ks + q4) ^ (l15 & 7)) * 8);
            #pragma unroll
            for (int hf = 0; hf < 2; hf++) {
                bf16x8 kf[4];
                #pragma unroll
                for (int mi = 0; mi < 4; mi++)
                    kf[mi] = *(const bf16x8*)&Ks[(hf * 64 + mi * 16 + l15) * 64 + ch];
                #pragma unroll
                for (int mi = 0; mi < 4; mi++)
                    st[hf][mi] = __builtin_amdgcn_mfma_f32_16x16x32_bf16(
                        kf[mi], qf[ks], st[hf][mi], 0, 0, 0);
            }
        }
        __builtin_amdgcn_s_setprio(0);

        // mask (last tile only) + row max: in-reg tree + 2 shuffle stages
        float rm = -1e30f;
        if (it == nkv - 1) {
            const int tq = qrow0 + l15;
            #pragma unroll
            for (int hf = 0; hf < 2; hf++)
                #pragma unroll
                for (int mi = 0; mi < 4; mi++)
                    #pragma unroll
                    for (int r = 0; r < 4; r++) {
                        float v = st[hf][mi][r];
                        if (k0 + hf * 64 + mi * 16 + q4 * 4 + r > tq) v = -1e30f;
                        st[hf][mi][r] = v;
                        rm = fmaxf(rm, v);
                    }
        } else {
            #pragma unroll
            for (int hf = 0; hf < 2; hf++)
                #pragma unroll
                for (int mi = 0; mi < 4; mi++)
                    #pragma unroll
                    for (int r = 0; r < 4; r++)
                        rm = fmaxf(rm, st[hf][mi][r]);
        }
        rm = fmaxf(rm, __shfl_xor(rm, 16, 64));
        rm = fmaxf(rm, __shfl_xor(rm, 32, 64));

        // Defer-max (T13): only update m (and rescale) when max grew past 8.
        const float mold = mstq;
        const bool need = __any(rm > mstq + 8.0f);
        if (need) mstq = fmaxf(mstq, rm);

        // exp2 + write P^T rows (q = l15) to Ps: 8B stores BEFORE B1 —
        // overlaps V-load latency, no cross-barrier register life.
        #pragma unroll
        for (int hf = 0; hf < 2; hf++)
            #pragma unroll
            for (int mi = 0; mi < 4; mi++) {
                bf16x4 p4;
                #pragma unroll
                for (int r = 0; r < 4; r++)
                    p4[r] = (__bf16)exp2f(st[hf][mi][r] - mstq);
                *(bf16x4*)&Ps[wave][l15][hf * 64 + mi * 16 + q4 * 4] = p4;
            }

        // alpha to row orientation: flat shuffles (only when max moved)
        if (need) {
            float alpha = exp2f(mold - mstq);
            float ar[4];
            #pragma unroll
            for (int r = 0; r < 4; r++)
                ar[r] = __shfl(alpha, q4 * 4 + r, 64);
            #pragma unroll
            for (int ni = 0; ni < 4; ni++)
                #pragma unroll
                for (int r = 0; r < 4; r++)
                    o[ni][r] *= ar[r];
            #pragma unroll
            for (int r = 0; r < 4; r++)
                ol[r] *= ar[r];
        }

        __syncthreads();   // B1: V(it) ready; all waves' Ks(it) reads done

        // Prefetch K(it+1) DIRECTLY into Ks (async LDS-writes land during
        // PV; PV never reads Ks). Block-uniform guard. Drained+published
        // by B2's vmcnt(0)+barrier.
        if (it + 1 < nkv) {
            const int k0n = k0 + 128;
            #pragma unroll
            for (int i = 0; i < 4; i++) {
                int rb = (wave * 4 + i) * 8;
                gl_lds16(Kb + (size_t)(k0n + rb + srow) * 64 + sKcol, Ks + rb * 64);
            }
        }

        // O += P V ; l += P·1  (contraction over kv=128, 4 ks-steps)
        __builtin_amdgcn_s_setprio(1);             // T5: favor MFMA cluster
        #pragma unroll
        for (int ks = 0; ks < 4; ks++) {
            bf16x8 pa = *(const bf16x8*)&Ps[wave][l15][ks * 32 + q4 * 8];
            bf16x8 vf[4];
            #pragma unroll
            for (int ni = 0; ni < 4; ni++) {
                const int pc = (((ks * 4 + q4) ^ l15) * 8);   // d&15 == l15
                vf[ni] = *(const bf16x8*)&Vs[(ni * 16 + l15) * 128 + pc];
            }
            #pragma unroll
            for (int ni = 0; ni < 4; ni++)
                o[ni] = __builtin_amdgcn_mfma_f32_16x16x32_bf16(pa, vf[ni], o[ni], 0, 0, 0);
            ol = __builtin_amdgcn_mfma_f32_16x16x32_bf16(pa, ones, ol, 0, 0, 0);
        }
        __builtin_amdgcn_s_setprio(0);

        __syncthreads();   // B2: Ks(it+1) drained+visible; Vs/Ps readers done
    }

    // Epilogue: O / l -> Oh[b,t,h,d] (= [4096,1024] rows)
    #pragma unroll
    for (int r = 0; r < 4; r++) {
        int t = qrow0 + q4 * 4 + r;
        float inv = 1.0f / ol[r];
        #pragma unroll
        for (int ni = 0; ni < 4; ni++) {
            int d = ni * 16 + l15;
            Oh[(((size_t)(b * 2048 + t)) * 16 + h) * 64 + d] = f2bf(o[ni][r] * inv);
        }
    }
}

// ---------------------------------------------------------------------------
// Kernel 3: out = Oh @ w_out^T (M=4096,N=1024,K=1024), fp32 out.
// BM=128, BN=64, BK=64: per-wave 64x32 acc[4][2] -> MFMA:ds_read = 16:12.
// Grid 16x32 = 512 blocks; LDS 24KB, (256,3).
// ---------------------------------------------------------------------------
__global__ __launch_bounds__(256, 3)
void outproj_kernel(const u16* __restrict__ A, const u16* __restrict__ W,
                    float* __restrict__ Cout)
{
    __shared__ __align__(16) u16 As[128 * 64];
    __shared__ __align__(16) u16 Bs[64 * 64];
    const int tid  = threadIdx.x;
    const int lane = tid & 63, wave = tid >> 6;
    const int l15  = lane & 15, q4 = lane >> 4;
    const int wm = (wave >> 1) * 64, wn = (wave & 1) * 32;
    const int m0 = blockIdx.y * 128, n0 = blockIdx.x * 64;
    const int srow = lane >> 3;
    const int scol = ((lane & 7) ^ srow) * 8;

    f32x4 acc[4][2];
    #pragma unroll
    for (int i = 0; i < 4; i++)
        #pragma unroll
        for (int j = 0; j < 2; j++) { f32x4 z = {}; acc[i][j] = z; }

    for (int k0 = 0; k0 < 1024; k0 += 64) {
        __syncthreads();
        #pragma unroll
        for (int i = 0; i < 6; i++) {           // 24 issues: 16 A + 8 B, 8-row each
            int id = wave * 6 + i;              // wave-uniform
            if (id < 16) {
                int rb = id * 8;
                gl_lds16(A + (size_t)(m0 + rb + srow) * 1024 + k0 + scol, As + rb * 64);
            } else {
                int rb = (id - 16) * 8;
                gl_lds16(W + (size_t)(n0 + rb + srow) * 1024 + k0 + scol, Bs + rb * 64);
            }
        }
        __syncthreads();
        #pragma unroll
        for (int ks = 0; ks < 2; ks++) {
            const int ch = (((ks * 4 + q4) ^ (l15 & 7)) * 8);
            bf16x8 af[4], bfr[2];
            #pragma unroll
            for (int i = 0; i < 4; i++)
                af[i]  = *(const bf16x8*)&As[(wm + i * 16 + l15) * 64 + ch];
            #pragma unroll
            for (int j = 0; j < 2; j++)
                bfr[j] = *(const bf16x8*)&Bs[(wn + j * 16 + l15) * 64 + ch];
            #pragma unroll
            for (int mi = 0; mi < 4; mi++)
                #pragma unroll
                for (int ni = 0; ni < 2; ni++)
                    acc[mi][ni] = __builtin_amdgcn_mfma_f32_16x16x32_bf16(
                        af[mi], bfr[ni], acc[mi][ni], 0, 0, 0);
        }
    }

    #pragma unroll
    for (int mi = 0; mi < 4; mi++)
        #pragma unroll
        for (int r = 0; r < 4; r++) {
            int row = m0 + wm + mi * 16 + q4 * 4 + r;
            #pragma unroll
            for (int ni = 0; ni < 2; ni++) {
                int col = n0 + wn + ni * 16 + l15;
                Cout[(size_t)row * 1024 + col] = acc[mi][ni][r];
            }
        }
}

extern "C" void kernel_launch(void* const* d_in, const int* in_sizes, int n_in,
                              void* d_out, int out_size, void* d_ws, size_t ws_size,
                              hipStream_t stream) {
    (void)in_sizes; (void)n_in; (void)out_size;
    const float* x     = (const float*)d_in[0];   // [2,2048,1024] fp32
    const float* cosp  = (const float*)d_in[1];   // [2048,64] fp32
    const float* sinp  = (const float*)d_in[2];   // [2048,64] fp32
    const float* w_qkv = (const float*)d_in[3];   // [3072,1024] fp32
    const float* w_out = (const float*)d_in[4];   // [1024,1024] fp32
    float* out = (float*)d_out;                   // [2,2048,1024] fp32

    const size_t NELEM = (size_t)2 * 2048 * 1024;  // 4,194,304
    // d_out (16.8 MB fp32): Q bf16 in lower half, X bf16 in upper half.
    // Both dead before outproj overwrites all of d_out.
    u16* Q   = (u16*)d_out;            // [b,h,t,d]
    u16* Xb  = (u16*)d_out + NELEM;    // [4096,1024] bf16
    // ws: K 8MB | Vt 8MB | Oh 8MB (+ Wqb aliasing Oh) [+ Wob @24MB if room]
    u16* K   = (u16*)d_ws;             // [b,h,t,d]
    u16* Vt  = K + NELEM;              // [b,h,d,t]
    u16* Oh  = Vt + NELEM;             // [b,t,h,d]
    u16* Wqb = Oh;                     // w_qkv bf16 — dead before attn writes Oh

    const bool big = ws_size >= (24u * 1024 * 1024 + 2u * 1024 * 1024);
    if (big) {
        u16* Wob = K + 3 * NELEM;      // own slot at ws+24MB (2MB)
        cvt_all_kernel<<<7168, 256, 0, stream>>>(x, w_qkv, w_out, Xb, Wqb, Wob,
                                                 262144);
        qkv_rope_kernel<<<dim3(24, 32), 256, 0, stream>>>(Xb, Wqb, cosp, sinp, Q, K, Vt);
        attn_kernel<<<1024, 256, 0, stream>>>(Q, K, Vt, Oh);
        outproj_kernel<<<dim3(16, 32), 256, 0, stream>>>(Oh, Wob, out);
    } else {
        u16* Wob = K;                  // w_out bf16 — written after attn (K dead)
        cvt_all_kernel<<<7168, 256, 0, stream>>>(x, w_qkv, w_out, Xb, Wqb, Wob, 0);
        qkv_rope_kernel<<<dim3(24, 32), 256, 0, stream>>>(Xb, Wqb, cosp, sinp, Q, K, Vt);
        attn_kernel<<<1024, 256, 0, stream>>>(Q, K, Vt, Oh);
        cvt_w_kernel<<<1024, 256, 0, stream>>>(w_out, Wob);
        outproj_kernel<<<dim3(16, 32), 256, 0, stream>>>(Oh, Wob, out);
    }
}

// Round 11
// 167.523 us; speedup vs baseline: 1.1157x; 1.0350x over previous
//
#include <hip/hip_runtime.h>

typedef unsigned short u16;
typedef __bf16 bf16x8 __attribute__((ext_vector_type(8)));
typedef __bf16 bf16x4 __attribute__((ext_vector_type(4)));
typedef float f32x4 __attribute__((ext_vector_type(4)));

__device__ __forceinline__ u16 f2bf(float f) {
    union { float f; unsigned int i; } v; v.f = f;
    unsigned int x = v.i;
    x += 0x7fffu + ((x >> 16) & 1u);   // round-to-nearest-even
    return (u16)(x >> 16);
}

// Async global->LDS 16B copy. LDS dest is wave-uniform base + lane*16.
__device__ __forceinline__ void gl_lds16(const u16* g, u16* l) {
    __builtin_amdgcn_global_load_lds(
        (const __attribute__((address_space(1))) void*)g,
        (__attribute__((address_space(3))) void*)l, 16, 0, 0);
}

// ---------------------------------------------------------------------------
// cvt: fp32 -> bf16, grid-stride. Up to three source ranges in one launch
// (x, w_qkv, and optionally w_out when the workspace has room for it).
// ---------------------------------------------------------------------------
__global__ __launch_bounds__(256, 2)
void cvt_all_kernel(const float* __restrict__ X, const float* __restrict__ Wq,
                    const float* __restrict__ Wo,
                    u16* __restrict__ Xb, u16* __restrict__ Wqb,
                    u16* __restrict__ Wob, int n3)
{
    const int n1 = 4194304 / 4;   // x chunks
    const int n2 = 3145728 / 4;   // w_qkv chunks
    int i = blockIdx.x * 256 + threadIdx.x;
    const int stride = gridDim.x * 256;
    for (; i < n1 + n2 + n3; i += stride) {
        float4 v;
        ushort4* dst;
        if (i < n1)           { v = ((const float4*)X)[i];            dst = (ushort4*)Xb  + i; }
        else if (i < n1 + n2) { v = ((const float4*)Wq)[i - n1];      dst = (ushort4*)Wqb + (i - n1); }
        else                  { v = ((const float4*)Wo)[i - n1 - n2]; dst = (ushort4*)Wob + (i - n1 - n2); }
        ushort4 o;
        o.x = f2bf(v.x); o.y = f2bf(v.y); o.z = f2bf(v.z); o.w = f2bf(v.w);
        *dst = o;
    }
}

__global__ __launch_bounds__(256, 2)
void cvt_w_kernel(const float* __restrict__ W, u16* __restrict__ Wb)
{
    int i = blockIdx.x * 256 + threadIdx.x;     // 262144 chunks, grid covers exactly
    float4 v = ((const float4*)W)[i];
    ushort4 o;
    o.x = f2bf(v.x); o.y = f2bf(v.y); o.z = f2bf(v.z); o.w = f2bf(v.w);
    ((ushort4*)Wb)[i] = o;
}

// ---------------------------------------------------------------------------
// Kernel 1: qkv = x @ w_qkv^T (M=4096,N=3072,K=1024), bf16 in, RoPE epilogue.
// m97 pattern: global_load_lds 16B staging into unpadded XOR-swizzled LDS.
// V-blocks (n0>=2048) use packed 8B epilogue stores (4 consecutive t / lane).
// ---------------------------------------------------------------------------
__global__ __launch_bounds__(256, 3)
void qkv_rope_kernel(const u16* __restrict__ X, const u16* __restrict__ W,
                     const float* __restrict__ Cos, const float* __restrict__ Sin,
                     u16* __restrict__ Qo, u16* __restrict__ Ko, u16* __restrict__ Vo)
{
    __shared__ __align__(16) u16 As[128 * 64];
    __shared__ __align__(16) u16 Bs[128 * 64];
    const int tid  = threadIdx.x;
    const int lane = tid & 63, wave = tid >> 6;
    const int l15  = lane & 15, q4 = lane >> 4;
    const int wm = (wave >> 1) * 64, wn = (wave & 1) * 64;
    const int m0 = blockIdx.y * 128, n0 = blockIdx.x * 128;
    const int srow = lane >> 3;
    const int scol = ((lane & 7) ^ srow) * 8;

    f32x4 acc[4][4];
    #pragma unroll
    for (int i = 0; i < 4; i++)
        #pragma unroll
        for (int j = 0; j < 4; j++) { f32x4 z = {}; acc[i][j] = z; }

    for (int k0 = 0; k0 < 1024; k0 += 64) {
        __syncthreads();
        #pragma unroll
        for (int i = 0; i < 4; i++) {
            int rb = wave * 32 + i * 8;
            gl_lds16(X + (size_t)(m0 + rb + srow) * 1024 + k0 + scol, As + rb * 64);
            gl_lds16(W + (size_t)(n0 + rb + srow) * 1024 + k0 + scol, Bs + rb * 64);
        }
        __syncthreads();
        #pragma unroll
        for (int ks = 0; ks < 2; ks++) {
            const int ch = (((4 * ks + q4) ^ (l15 & 7)) * 8);
            bf16x8 af[4], bfr[4];
            #pragma unroll
            for (int i = 0; i < 4; i++) {
                af[i]  = *(const bf16x8*)&As[(wm + i * 16 + l15) * 64 + ch];
                bfr[i] = *(const bf16x8*)&Bs[(wn + i * 16 + l15) * 64 + ch];
            }
            #pragma unroll
            for (int mi = 0; mi < 4; mi++)
                #pragma unroll
                for (int ni = 0; ni < 4; ni++)
                    acc[mi][ni] = __builtin_amdgcn_mfma_f32_16x16x32_bf16(
                        af[mi], bfr[ni], acc[mi][ni], 0, 0, 0);
        }
    }

    if (n0 >= 2048) {
        // Pure-V block: packed stores, 4 t-consecutive values per 8B.
        #pragma unroll
        for (int mi = 0; mi < 4; mi++) {
            int t0row = m0 + wm + mi * 16 + q4 * 4;       // global m, 4-aligned
            int b = t0row >> 11, t0 = t0row & 2047;
            #pragma unroll
            for (int ni = 0; ni < 4; ni++) {
                int col = n0 + wn + ni * 16 + l15;
                int hh  = (col >> 6) & 15;
                int d   = col & 63;
                ushort4 pk;
                pk.x = f2bf(acc[mi][ni][0]); pk.y = f2bf(acc[mi][ni][1]);
                pk.z = f2bf(acc[mi][ni][2]); pk.w = f2bf(acc[mi][ni][3]);
                *(ushort4*)&Vo[(((size_t)(b * 16 + hh)) * 64 + d) * 2048 + t0] = pk;
            }
        }
    } else {
        // Q/K block: RoPE epilogue. C/D layout col=lane&15, row=quad*4+reg.
        #pragma unroll
        for (int mi = 0; mi < 4; mi++) {
            #pragma unroll
            for (int r = 0; r < 4; r++) {
                int row = m0 + wm + mi * 16 + q4 * 4 + r;
                int b = row >> 11, t = row & 2047;
                #pragma unroll
                for (int ni = 0; ni < 4; ni++) {
                    int col = n0 + wn + ni * 16 + l15;
                    float v = acc[mi][ni][r];
                    int sec = col >> 10;
                    int hh  = (col >> 6) & 15;
                    int d   = col & 63;
                    float cs = Cos[t * 64 + d];
                    float sn = Sin[t * 64 + d];
                    float partner = acc[mi][ni ^ 2][r];   // col ^ 32, same lane
                    float rot = (d < 32) ? -partner : partner;
                    v = v * cs + rot * sn;
                    u16* dst = (sec == 0) ? Qo : Ko;
                    dst[(((size_t)(b * 16 + hh)) * 2048 + t) * 64 + d] = f2bf(v);
                }
            }
        }
    }
}

// ---------------------------------------------------------------------------
// Kernel 2: causal flash attention, S^T formulation, KV-tile = 128.
// R8 structure + T5 setprio (R10: attn dropped below the 43.5us top-5
// cutoff — setprio kept). 2-barrier loop, K(it+1) gl_lds16-prefetched into
// Ks during PV; VGPR 84, FETCH 12.4MB, WRITE 8.2MB, no spill.
// Occupancy axis closed both ways (R6: 2/CU -10%; R9: 8-wave -23%);
// 4-wave x 3 blocks/CU is this structure's optimum. Defer-max THR=8.
// ---------------------------------------------------------------------------
__global__ __launch_bounds__(256, 3)
void attn_kernel(const u16* __restrict__ Q, const u16* __restrict__ Kg,
                 const u16* __restrict__ Vt, u16* __restrict__ Oh)
{
    __shared__ __align__(16) u16 Ks[128 * 64];    // [kv][d]   8-chunk rows, ^(row&7)
    __shared__ __align__(16) u16 Vs[64 * 128];    // [d][kv]  16-chunk rows, ^(d&15)
    __shared__ __align__(16) __bf16 Ps[4][16][136];

    const int bx = blockIdx.x;
    const int xcd = bx & 7;
    const int i8  = bx >> 3;            // 0..127 per XCD
    const int bh  = xcd * 4 + (i8 & 3); // 4 heads per XCD
    const int qt  = 31 - (i8 >> 2);     // longest q-tiles first (LPT)
    const int b = bh >> 4, h = bh & 15;
    const int tid = threadIdx.x, wave = tid >> 6, lane = tid & 63;
    const int l15 = lane & 15, q4 = lane >> 4;
    const int srow = lane >> 3;
    const int sKcol = ((lane & 7) ^ srow) * 8;

    const size_t head_off = (size_t)bh * 2048 * 64;
    const u16* Qb = Q  + head_off;
    const u16* Kb = Kg + head_off;
    const u16* Vb = Vt + head_off;     // [d][t] per head

    const int qrow0 = qt * 64 + wave * 16;   // this wave's 16 q-rows

    // Q fragments (B operand): B[n=l15][k=q4*8+j+32*ks], pre-scaled by
    // 0.125*log2(e): softmax moves to exp2 domain.
    const float QSCALE = 0.18033688f;
    bf16x8 qf[2];
    #pragma unroll
    for (int ks = 0; ks < 2; ks++) {
        bf16x8 t = *(const bf16x8*)(Qb + (size_t)(qrow0 + l15) * 64 + ks * 32 + q4 * 8);
        #pragma unroll
        for (int j = 0; j < 8; j++) t[j] = (__bf16)((float)t[j] * QSCALE);
        qf[ks] = t;
    }

    bf16x8 ones;
    #pragma unroll
    for (int j = 0; j < 8; j++) ones[j] = (__bf16)1.0f;

    f32x4 o[4];                       // O rows q=qrow0+q4*4+r, cols d=ni*16+l15
    f32x4 ol = {};                    // row-sum accumulator
    float mstq = -1e30f;              // running max (log2 domain), lane's q=l15
    #pragma unroll
    for (int ni = 0; ni < 4; ni++) { f32x4 z = {}; o[ni] = z; }

    const int nkv = (qt >> 1) + 1;     // 128-wide kv tiles (block-uniform)

    // Prologue: stage K(0), one barrier (vmcnt(0) drains it).
    #pragma unroll
    for (int i = 0; i < 4; i++) {
        int rb = (wave * 4 + i) * 8;
        gl_lds16(Kb + (size_t)(rb + srow) * 64 + sKcol, Ks + rb * 64);
    }
    __syncthreads();                   // K(0) in LDS, visible block-wide

    for (int it = 0; it < nkv; it++) {
        const int k0 = it * 128;
        // Issue V(it): in flight through the whole S phase.
        // (Vs free: prior PV readers drained at B2 / prologue barrier.)
        #pragma unroll
        for (int i = 0; i < 4; i++) {
            int rb = (wave * 4 + i) * 4;
            int d  = rb + (lane >> 4);
            int cl = ((lane & 15) ^ (d & 15)) * 8;
            gl_lds16(Vb + (size_t)d * 2048 + k0 + cl, Vs + rb * 128);
        }

        // S^T = K Q^T : st[half][mi][r]: kv = half*64+mi*16+q4*4+r, q = l15
        f32x4 st[2][4];
        #pragma unroll
        for (int hf = 0; hf < 2; hf++)
            #pragma unroll
            for (int mi = 0; mi < 4; mi++) { f32x4 z = {}; st[hf][mi] = z; }
        __builtin_amdgcn_s_setprio(1);             // T5: favor MFMA cluster
        #pragma unroll
        for (int ks = 0; ks < 2; ks++) {
            const int ch = (((4 * ks + q4) ^ (l15 & 7)) * 8);
            #pragma unroll
            for (int hf = 0; hf < 2; hf++) {
                bf16x8 kf[4];
                #pragma unroll
                for (int mi = 0; mi < 4; mi++)
                    kf[mi] = *(const bf16x8*)&Ks[(hf * 64 + mi * 16 + l15) * 64 + ch];
                #pragma unroll
                for (int mi = 0; mi < 4; mi++)
                    st[hf][mi] = __builtin_amdgcn_mfma_f32_16x16x32_bf16(
                        kf[mi], qf[ks], st[hf][mi], 0, 0, 0);
            }
        }
        __builtin_amdgcn_s_setprio(0);

        // mask (last tile only) + row max: in-reg tree + 2 shuffle stages
        float rm = -1e30f;
        if (it == nkv - 1) {
            const int tq = qrow0 + l15;
            #pragma unroll
            for (int hf = 0; hf < 2; hf++)
                #pragma unroll
                for (int mi = 0; mi < 4; mi++)
                    #pragma unroll
                    for (int r = 0; r < 4; r++) {
                        float v = st[hf][mi][r];
                        if (k0 + hf * 64 + mi * 16 + q4 * 4 + r > tq) v = -1e30f;
                        st[hf][mi][r] = v;
                        rm = fmaxf(rm, v);
                    }
        } else {
            #pragma unroll
            for (int hf = 0; hf < 2; hf++)
                #pragma unroll
                for (int mi = 0; mi < 4; mi++)
                    #pragma unroll
                    for (int r = 0; r < 4; r++)
                        rm = fmaxf(rm, st[hf][mi][r]);
        }
        rm = fmaxf(rm, __shfl_xor(rm, 16, 64));
        rm = fmaxf(rm, __shfl_xor(rm, 32, 64));

        // Defer-max (T13): only update m (and rescale) when max grew past 8.
        const float mold = mstq;
        const bool need = __any(rm > mstq + 8.0f);
        if (need) mstq = fmaxf(mstq, rm);

        // exp2 + write P^T rows (q = l15) to Ps: 8B stores BEFORE B1 —
        // overlaps V-load latency, no cross-barrier register life.
        #pragma unroll
        for (int hf = 0; hf < 2; hf++)
            #pragma unroll
            for (int mi = 0; mi < 4; mi++) {
                bf16x4 p4;
                #pragma unroll
                for (int r = 0; r < 4; r++)
                    p4[r] = (__bf16)exp2f(st[hf][mi][r] - mstq);
                *(bf16x4*)&Ps[wave][l15][hf * 64 + mi * 16 + q4 * 4] = p4;
            }

        // alpha to row orientation: flat shuffles (only when max moved)
        if (need) {
            float alpha = exp2f(mold - mstq);
            float ar[4];
            #pragma unroll
            for (int r = 0; r < 4; r++)
                ar[r] = __shfl(alpha, q4 * 4 + r, 64);
            #pragma unroll
            for (int ni = 0; ni < 4; ni++)
                #pragma unroll
                for (int r = 0; r < 4; r++)
                    o[ni][r] *= ar[r];
            #pragma unroll
            for (int r = 0; r < 4; r++)
                ol[r] *= ar[r];
        }

        __syncthreads();   // B1: V(it) ready; all waves' Ks(it) reads done

        // Prefetch K(it+1) DIRECTLY into Ks (async LDS-writes land during
        // PV; PV never reads Ks). Block-uniform guard. Drained+published
        // by B2's vmcnt(0)+barrier.
        if (it + 1 < nkv) {
            const int k0n = k0 + 128;
            #pragma unroll
            for (int i = 0; i < 4; i++) {
                int rb = (wave * 4 + i) * 8;
                gl_lds16(Kb + (size_t)(k0n + rb + srow) * 64 + sKcol, Ks + rb * 64);
            }
        }

        // O += P V ; l += P·1  (contraction over kv=128, 4 ks-steps)
        __builtin_amdgcn_s_setprio(1);             // T5: favor MFMA cluster
        #pragma unroll
        for (int ks = 0; ks < 4; ks++) {
            bf16x8 pa = *(const bf16x8*)&Ps[wave][l15][ks * 32 + q4 * 8];
            bf16x8 vf[4];
            #pragma unroll
            for (int ni = 0; ni < 4; ni++) {
                const int pc = (((ks * 4 + q4) ^ l15) * 8);   // d&15 == l15
                vf[ni] = *(const bf16x8*)&Vs[(ni * 16 + l15) * 128 + pc];
            }
            #pragma unroll
            for (int ni = 0; ni < 4; ni++)
                o[ni] = __builtin_amdgcn_mfma_f32_16x16x32_bf16(pa, vf[ni], o[ni], 0, 0, 0);
            ol = __builtin_amdgcn_mfma_f32_16x16x32_bf16(pa, ones, ol, 0, 0, 0);
        }
        __builtin_amdgcn_s_setprio(0);

        __syncthreads();   // B2: Ks(it+1) drained+visible; Vs/Ps readers done
    }

    // Epilogue: O / l -> Oh[b,t,h,d] (= [4096,1024] rows)
    #pragma unroll
    for (int r = 0; r < 4; r++) {
        int t = qrow0 + q4 * 4 + r;
        float inv = 1.0f / ol[r];
        #pragma unroll
        for (int ni = 0; ni < 4; ni++) {
            int d = ni * 16 + l15;
            Oh[(((size_t)(b * 2048 + t)) * 16 + h) * 64 + d] = f2bf(o[ni][r] * inv);
        }
    }
}

// ---------------------------------------------------------------------------
// Kernel 3: out = Oh @ w_out^T (M=4096,N=1024,K=1024), fp32 out.
// REVERTED to pre-session shape: 64x64 tiles, BK=128, grid 16x64 = 1024
// blocks = 4/CU = 16 waves/CU. Session evidence (attn R6/R9 dose-response)
// says these kernels are per-wave latency-bound and respond to resident
// waves; the R0 reshape (128x64, 512 blocks = 2/CU) halved TLP for a
// staging-ratio gain that never materialized. Small state (acc[2][2] ~60
// VGPR) -> no spill risk at the (256,4) 128-VGPR cap. LDS 32KB x4 = 128KB.
// ---------------------------------------------------------------------------
__global__ __launch_bounds__(256, 4)
void outproj_kernel(const u16* __restrict__ A, const u16* __restrict__ W,
                    float* __restrict__ Cout)
{
    __shared__ __align__(16) u16 As[64 * 128];
    __shared__ __align__(16) u16 Bs[64 * 128];
    const int tid  = threadIdx.x;
    const int lane = tid & 63, wave = tid >> 6;
    const int l15  = lane & 15, q4 = lane >> 4;
    const int wm = (wave >> 1) * 32, wn = (wave & 1) * 32;
    const int m0 = blockIdx.y * 64, n0 = blockIdx.x * 64;

    f32x4 acc[2][2];
    #pragma unroll
    for (int i = 0; i < 2; i++)
        #pragma unroll
        for (int j = 0; j < 2; j++) { f32x4 z = {}; acc[i][j] = z; }

    for (int k0 = 0; k0 < 1024; k0 += 128) {
        __syncthreads();
        #pragma unroll
        for (int i = 0; i < 8; i++) {           // 32 issues: 16 A + 16 B, 4-row each
            int id = wave * 8 + i;
            int rb = (id & 15) * 4;
            int row = rb + (lane >> 4);
            int cl  = ((lane & 15) ^ (row & 15)) * 8;
            if (id < 16)
                gl_lds16(A + (size_t)(m0 + row) * 1024 + k0 + cl, As + rb * 128);
            else
                gl_lds16(W + (size_t)(n0 + row) * 1024 + k0 + cl, Bs + rb * 128);
        }
        __syncthreads();
        #pragma unroll
        for (int ks = 0; ks < 4; ks++) {
            const int ch = (((ks * 4 + q4) ^ l15) * 8);
            bf16x8 af[2], bfr[2];
            #pragma unroll
            for (int i = 0; i < 2; i++) {
                af[i]  = *(const bf16x8*)&As[(wm + i * 16 + l15) * 128 + ch];
                bfr[i] = *(const bf16x8*)&Bs[(wn + i * 16 + l15) * 128 + ch];
            }
            #pragma unroll
            for (int mi = 0; mi < 2; mi++)
                #pragma unroll
                for (int ni = 0; ni < 2; ni++)
                    acc[mi][ni] = __builtin_amdgcn_mfma_f32_16x16x32_bf16(
                        af[mi], bfr[ni], acc[mi][ni], 0, 0, 0);
        }
    }

    #pragma unroll
    for (int mi = 0; mi < 2; mi++)
        #pragma unroll
        for (int r = 0; r < 4; r++) {
            int row = m0 + wm + mi * 16 + q4 * 4 + r;
            #pragma unroll
            for (int ni = 0; ni < 2; ni++) {
                int col = n0 + wn + ni * 16 + l15;
                Cout[(size_t)row * 1024 + col] = acc[mi][ni][r];
            }
        }
}

extern "C" void kernel_launch(void* const* d_in, const int* in_sizes, int n_in,
                              void* d_out, int out_size, void* d_ws, size_t ws_size,
                              hipStream_t stream) {
    (void)in_sizes; (void)n_in; (void)out_size;
    const float* x     = (const float*)d_in[0];   // [2,2048,1024] fp32
    const float* cosp  = (const float*)d_in[1];   // [2048,64] fp32
    const float* sinp  = (const float*)d_in[2];   // [2048,64] fp32
    const float* w_qkv = (const float*)d_in[3];   // [3072,1024] fp32
    const float* w_out = (const float*)d_in[4];   // [1024,1024] fp32
    float* out = (float*)d_out;                   // [2,2048,1024] fp32

    const size_t NELEM = (size_t)2 * 2048 * 1024;  // 4,194,304
    // d_out (16.8 MB fp32): Q bf16 in lower half, X bf16 in upper half.
    // Both dead before outproj overwrites all of d_out.
    u16* Q   = (u16*)d_out;            // [b,h,t,d]
    u16* Xb  = (u16*)d_out + NELEM;    // [4096,1024] bf16
    // ws: K 8MB | Vt 8MB | Oh 8MB (+ Wqb aliasing Oh) [+ Wob @24MB if room]
    u16* K   = (u16*)d_ws;             // [b,h,t,d]
    u16* Vt  = K + NELEM;              // [b,h,d,t]
    u16* Oh  = Vt + NELEM;             // [b,t,h,d]
    u16* Wqb = Oh;                     // w_qkv bf16 — dead before attn writes Oh

    const bool big = ws_size >= (24u * 1024 * 1024 + 2u * 1024 * 1024);
    if (big) {
        u16* Wob = K + 3 * NELEM;      // own slot at ws+24MB (2MB)
        cvt_all_kernel<<<7168, 256, 0, stream>>>(x, w_qkv, w_out, Xb, Wqb, Wob,
                                                 262144);
        qkv_rope_kernel<<<dim3(24, 32), 256, 0, stream>>>(Xb, Wqb, cosp, sinp, Q, K, Vt);
        attn_kernel<<<1024, 256, 0, stream>>>(Q, K, Vt, Oh);
        outproj_kernel<<<dim3(16, 64), 256, 0, stream>>>(Oh, Wob, out);
    } else {
        u16* Wob = K;                  // w_out bf16 — written after attn (K dead)
        cvt_all_kernel<<<7168, 256, 0, stream>>>(x, w_qkv, w_out, Xb, Wqb, Wob, 0);
        qkv_rope_kernel<<<dim3(24, 32), 256, 0, stream>>>(Xb, Wqb, cosp, sinp, Q, K, Vt);
        attn_kernel<<<1024, 256, 0, stream>>>(Q, K, Vt, Oh);
        cvt_w_kernel<<<1024, 256, 0, stream>>>(w_out, Wob);
        outproj_kernel<<<dim3(16, 64), 256, 0, stream>>>(Oh, Wob, out);
    }
}